// Round 1
// 1694.284 us; speedup vs baseline: 1.1778x; 1.1778x over previous
//
#include <hip/hip_runtime.h>
#include <hip/hip_bf16.h>

// ---------------------------------------------------------------------------
// 2-layer GAT on MI355X.
// R2 -> R3 changes:
//  * GEMM1 rewritten as 256x256 tile, BK=64, 8 waves (2x4), double-buffered
//    128 KiB LDS, prefetch-next-tile-then-compute schedule (one barrier per
//    K-tile instead of two, loads in flight across the whole MFMA cluster),
//    s_setprio(1) around the MFMA cluster, XCD-aware block swizzle.
//    LDS stays in MFMA-fragment order (lane-linear) -> zero bank conflicts
//    on both global_load_lds and ds_read_b128, no XOR swizzle needed.
//  * M1PAD 60032 -> 60160 (multiple of 256); pad rows of featb zeroed.
//  * GEMM2 (tiny) keeps the old 128x128 single-buffer kernel.
// ---------------------------------------------------------------------------

typedef __bf16 bf16;
typedef bf16 bf16x8 __attribute__((ext_vector_type(8)));
typedef float f32x4 __attribute__((ext_vector_type(4)));

#define N_SRC0V 60000
#define N_DST0V 15000
#define N_DST1V 4000
#define E0V 240000
#define E1V 64000
#define HD1V 2048
#define K1V 2048
#define M1PAD 60160
#define M2PAD 15104

// 128-tile params (GEMM2 only)
#define BM 128
#define BN 128
#define BK 64

// 256-tile params (GEMM1)
#define GBM 256
#define GBN 256
#define GBK 64

__device__ __forceinline__ void gload16(const void* g, void* l) {
  __builtin_amdgcn_global_load_lds(
      (__attribute__((address_space(1))) void*)(g),
      (__attribute__((address_space(3))) void*)(l), 16, 0, 0);
}

// ---------------- feat fp32 -> bf16, 8 elems/thread ----------------
__global__ void k_convert(const float* __restrict__ x, bf16* __restrict__ y, long n8) {
  long i = (long)blockIdx.x * 256 + threadIdx.x;
  if (i >= n8) return;
  const float4* xp = (const float4*)(x + i * 8);
  float4 a = xp[0], b = xp[1];
  bf16x8 o;
  o[0] = (bf16)a.x; o[1] = (bf16)a.y; o[2] = (bf16)a.z; o[3] = (bf16)a.w;
  o[4] = (bf16)b.x; o[5] = (bf16)b.y; o[6] = (bf16)b.z; o[7] = (bf16)b.w;
  *(bf16x8*)(y + i * 8) = o;
}

// ---------------- W[R][C] fp32 -> WT[C][R] bf16 ----------------
__global__ void k_transpose_bf16(const float* __restrict__ W, bf16* __restrict__ WT,
                                 int R, int C) {
  __shared__ float tile[32][33];
  int tx = threadIdx.x & 31, ty = threadIdx.x >> 5;
  int c0 = blockIdx.x * 32, r0 = blockIdx.y * 32;
  for (int i = ty; i < 32; i += 8) {
    int r = r0 + i, c = c0 + tx;
    tile[i][tx] = (r < R && c < C) ? W[(size_t)r * C + c] : 0.f;
  }
  __syncthreads();
  for (int i = ty; i < 32; i += 8) {
    int c = c0 + i, r = r0 + tx;
    if (c < C && r < R) WT[(size_t)c * R + r] = (bf16)tile[tx][i];
  }
}

// ---------------- GEMM1: 256x256 tile, dbuf, 8 waves -----------------------
// C[M][N] = A[M][K] * BT[N][K]^T, all dims multiples of tile sizes.
// LDS fragment order: seg = rb*2+kb (rb = 16-row block in [0,16), kb = 32-k
// block). Lane L of seg holds X[rb*16 + (L&15)][kb*32 + (L>>4)*8 .. +7].
// All LDS traffic is base + lane*16B -> conflict-free.
// Schedule per K-tile: issue 8 prefetch global_load_lds for tile t+1 into the
// other buffer, then 2x(12 ds_read + 32 MFMA in setprio(1)), then ONE
// __syncthreads() (drains the prefetch, joins waves before overwrite).
__global__ __launch_bounds__(512, 2) void k_gemm256_bt(
    const bf16* __restrict__ A, const bf16* __restrict__ BT,
    bf16* __restrict__ C, int N, int K) {
  extern __shared__ char smem_raw[];
  bf16* smem = (bf16*)smem_raw;   // [2][16384 A + 16384 B]
  const int tid = threadIdx.x;
  const int lane = tid & 63;
  const int wv = tid >> 6;        // 0..7
  const int wm = wv >> 2;         // 0..1 -> 128-row half
  const int wn = wv & 3;          // 0..3 -> 64-col quarter
  const int lr = lane & 15, lq = lane >> 4;

  // XCD-aware swizzle (bijective: nwg % 8 == 0 for GEMM1's 8x235 grid)
  int nwg = gridDim.x * gridDim.y;
  int flat = blockIdx.y * gridDim.x + blockIdx.x;
  if ((nwg & 7) == 0) {
    int cpx = nwg >> 3;
    flat = (flat & 7) * cpx + (flat >> 3);
  }
  const int m0 = (flat / gridDim.x) * GBM;
  const int n0 = (flat % gridDim.x) * GBN;

  const f32x4 vzero = {0.f, 0.f, 0.f, 0.f};
  f32x4 acc[8][4];
#pragma unroll
  for (int i = 0; i < 8; ++i)
#pragma unroll
    for (int j = 0; j < 4; ++j) acc[i][j] = vzero;

  // stage one 256x64 A-tile + 256x64 B-tile (fragment order) into buffer b
  auto stage = [&](int b, int k0) {
    bf16* sAb = smem + b * 32768;
    bf16* sBb = sAb + 16384;
#pragma unroll
    for (int it = 0; it < 4; ++it) {
      int c = it * 512 + tid;       // 0..2047, seg = c>>6 wave-uniform
      int seg = c >> 6;
      int ln = c & 63;
      int row = (seg >> 1) * 16 + (ln & 15);
      int col = (seg & 1) * 32 + (ln >> 4) * 8;
      gload16(A + (size_t)(m0 + row) * K + k0 + col, &sAb[c * 8]);
      gload16(BT + (size_t)(n0 + row) * K + k0 + col, &sBb[c * 8]);
    }
  };

  const int NT = K / GBK;
  stage(0, 0);
  __syncthreads();

  for (int kt = 0; kt < NT; ++kt) {
    const int cur = kt & 1;
    bf16* sAb = smem + cur * 32768;
    bf16* sBb = sAb + 16384;
    if (kt + 1 < NT) stage(cur ^ 1, (kt + 1) * GBK);  // issue early, drain late
#pragma unroll
    for (int kb = 0; kb < 2; ++kb) {
      bf16x8 af[8], bfr[4];
#pragma unroll
      for (int i = 0; i < 8; ++i)
        af[i] = *(const bf16x8*)&sAb[(((wm * 8 + i) * 2 + kb) * 64 + lane) * 8];
#pragma unroll
      for (int j = 0; j < 4; ++j)
        bfr[j] = *(const bf16x8*)&sBb[(((wn * 4 + j) * 2 + kb) * 64 + lane) * 8];
      __builtin_amdgcn_s_setprio(1);
#pragma unroll
      for (int i = 0; i < 8; ++i)
#pragma unroll
        for (int j = 0; j < 4; ++j)
          acc[i][j] = __builtin_amdgcn_mfma_f32_16x16x32_bf16(af[i], bfr[j], acc[i][j], 0, 0, 0);
      __builtin_amdgcn_s_setprio(0);
    }
    __syncthreads();   // vmcnt(0)+lgkmcnt(0)+barrier: prefetch landed, reads done
  }

  // epilogue: D row=(lane>>4)*4+reg, col=lane&15  [m89/m91-verified layout]
#pragma unroll
  for (int i = 0; i < 8; ++i)
#pragma unroll
    for (int j = 0; j < 4; ++j) {
      int row = m0 + wm * 128 + i * 16 + lq * 4;
      int col = n0 + wn * 64 + j * 16 + lr;
#pragma unroll
      for (int r = 0; r < 4; ++r)
        C[(size_t)(row + r) * N + col] = (bf16)acc[i][j][r];
    }
}

// ---------------- GEMM2 (small): 128x128 tile, 4 waves 2x2 ------------------
template <typename OutT>
__global__ __launch_bounds__(256) void k_gemm_bt(
    const bf16* __restrict__ A, const bf16* __restrict__ BT,
    OutT* __restrict__ C, int N, int K) {
  __shared__ bf16 sA[BM * BK];
  __shared__ bf16 sB[BN * BK];
  const int tid = threadIdx.x;
  const int lane = tid & 63;
  const int wv = tid >> 6;
  const int wm = wv >> 1, wn = wv & 1;
  const int lr = lane & 15, lq = lane >> 4;
  const int m0 = blockIdx.y * BM;
  const int n0 = blockIdx.x * BN;

  const f32x4 vzero = {0.f, 0.f, 0.f, 0.f};
  f32x4 acc[4][4];
#pragma unroll
  for (int i = 0; i < 4; ++i)
#pragma unroll
    for (int j = 0; j < 4; ++j) acc[i][j] = vzero;

  for (int k0 = 0; k0 < K; k0 += BK) {
#pragma unroll
    for (int it = 0; it < 4; ++it) {
      int c = it * 256 + tid;           // 0..1023
      int seg = c >> 6;                 // wave-uniform (it*4 + wv)
      int ln = c & 63;
      int row = (seg >> 1) * 16 + (ln & 15);
      int col = (seg & 1) * 32 + (ln >> 4) * 8;
      gload16(A + (size_t)(m0 + row) * K + k0 + col, &sA[c * 8]);
      gload16(BT + (size_t)(n0 + row) * K + k0 + col, &sB[c * 8]);
    }
    __syncthreads();
#pragma unroll
    for (int kk = 0; kk < BK; kk += 32) {
      const int kb = kk >> 5;
      bf16x8 af[4], bfr[4];
#pragma unroll
      for (int i = 0; i < 4; ++i)
        af[i] = *(const bf16x8*)&sA[(((wm * 4 + i) * 2 + kb) * 64 + lane) * 8];
#pragma unroll
      for (int j = 0; j < 4; ++j)
        bfr[j] = *(const bf16x8*)&sB[(((wn * 4 + j) * 2 + kb) * 64 + lane) * 8];
#pragma unroll
      for (int i = 0; i < 4; ++i)
#pragma unroll
        for (int j = 0; j < 4; ++j)
          acc[i][j] = __builtin_amdgcn_mfma_f32_16x16x32_bf16(af[i], bfr[j], acc[i][j], 0, 0, 0);
    }
    __syncthreads();
  }
#pragma unroll
  for (int i = 0; i < 4; ++i)
#pragma unroll
    for (int j = 0; j < 4; ++j) {
      int row = m0 + wm * 64 + i * 16 + lq * 4;
      int col = n0 + wn * 64 + j * 16 + lr;
#pragma unroll
      for (int r = 0; r < 4; ++r)
        C[(size_t)(row + r) * N + col] = (OutT)acc[i][j][r];
    }
}

// ---------------- layer1 el/er: h bf16 [row][2048], 8 heads x 256 ----------
__global__ void k_el_er1(const bf16* __restrict__ h, const float* __restrict__ al,
                         const float* __restrict__ ar, float* __restrict__ el,
                         float* __restrict__ er, int n_dst) {
  int row = blockIdx.x;
  int t = threadIdx.x;               // head = t>>5, 32 threads/head, 8 d each
  bf16x8 hv = *(const bf16x8*)(h + (size_t)row * 2048 + t * 8);
  float pl = 0.f, pr = 0.f;
#pragma unroll
  for (int e = 0; e < 8; ++e) {
    float v = (float)hv[e];
    pl += v * al[t * 8 + e];
    pr += v * ar[t * 8 + e];
  }
#pragma unroll
  for (int off = 16; off >= 1; off >>= 1) {
    pl += __shfl_down(pl, off);
    pr += __shfl_down(pr, off);
  }
  if ((t & 31) == 0) {
    el[(size_t)row * 8 + (t >> 5)] = pl;
    if (row < n_dst) er[(size_t)row * 8 + (t >> 5)] = pr;
  }
}

// ---------------- layer2 el/er: h fp32 [row][128], 1 head ----------------
__global__ void k_el_er2(const float* __restrict__ h, const float* __restrict__ al,
                         const float* __restrict__ ar, float* __restrict__ el,
                         float* __restrict__ er, int n_el, int n_dst) {
  int t = threadIdx.x;
  int row = blockIdx.x * 16 + (t >> 4);   // 16 rows/block, 16 threads/row
  int s = t & 15;
  const float* hp = h + (size_t)row * 128 + s * 8;
  float4 a = *(const float4*)hp;
  float4 b = *(const float4*)(hp + 4);
  float pl = a.x * al[s * 8] + a.y * al[s * 8 + 1] + a.z * al[s * 8 + 2] + a.w * al[s * 8 + 3]
           + b.x * al[s * 8 + 4] + b.y * al[s * 8 + 5] + b.z * al[s * 8 + 6] + b.w * al[s * 8 + 7];
  float pr = a.x * ar[s * 8] + a.y * ar[s * 8 + 1] + a.z * ar[s * 8 + 2] + a.w * ar[s * 8 + 3]
           + b.x * ar[s * 8 + 4] + b.y * ar[s * 8 + 5] + b.z * ar[s * 8 + 6] + b.w * ar[s * 8 + 7];
#pragma unroll
  for (int off = 8; off >= 1; off >>= 1) {
    pl += __shfl_down(pl, off);
    pr += __shfl_down(pr, off);
  }
  if (s == 0 && row < n_el) {
    el[row] = pl;
    if (row < n_dst) er[row] = pr;
  }
}

// ---------------- CSR build ----------------
__global__ void k_zero(int* __restrict__ p, int n) {
  int i = blockIdx.x * 256 + threadIdx.x;
  if (i < n) p[i] = 0;
}
__global__ void k_hist(const int* __restrict__ d, int E, int* __restrict__ counts) {
  int e = blockIdx.x * 256 + threadIdx.x;
  if (e < E) atomicAdd(&counts[d[e]], 1);
}
__global__ void k_scan(const int* __restrict__ counts, int n, int* __restrict__ offs,
                       int* __restrict__ cursor) {
  __shared__ int part[1024];
  int t = threadIdx.x;
  int per = (n + 1023) >> 10;
  int b = t * per;
  int e = b + per < n ? b + per : n;
  int s = 0;
  for (int i = b; i < e; ++i) s += counts[i];
  part[t] = s;
  __syncthreads();
  for (int off = 1; off < 1024; off <<= 1) {
    int v = 0;
    if (t >= off) v = part[t - off];
    __syncthreads();
    part[t] += v;
    __syncthreads();
  }
  int run = (t == 0) ? 0 : part[t - 1];
  for (int i = b; i < e; ++i) { offs[i] = run; cursor[i] = run; run += counts[i]; }
  if (t == 1023) offs[n] = run;
}
__global__ void k_scatter(const int* __restrict__ d, int E, int* __restrict__ cursor,
                          int* __restrict__ eperm) {
  int e = blockIdx.x * 256 + threadIdx.x;
  if (e < E) eperm[atomicAdd(&cursor[d[e]], 1)] = e;
}

// ---------------- per-(dst,head) softmax max/denominator ----------------
__global__ void k_stats(const int* __restrict__ offs, const int* __restrict__ eperm,
                        const int* __restrict__ srcv, const float* __restrict__ el,
                        const float* __restrict__ er, int n_dst, int H,
                        float* __restrict__ emax, float* __restrict__ eden) {
  int idx = blockIdx.x * 256 + threadIdx.x;
  if (idx >= n_dst * H) return;
  int dn = idx / H, hh = idx - dn * H;
  int s0 = offs[dn], s1 = offs[dn + 1];
  float erv = er[idx];
  float mx = -1e30f;
  for (int p = s0; p < s1; ++p) {
    float v = el[srcv[eperm[p]] * H + hh] + erv;
    v = v > 0.f ? v : 0.2f * v;
    mx = fmaxf(mx, v);
  }
  if (s1 == s0) mx = 0.f;  // zero in-degree guard (matches isfinite guard)
  float s = 0.f;
  for (int p = s0; p < s1; ++p) {
    float v = el[srcv[eperm[p]] * H + hh] + erv;
    v = v > 0.f ? v : 0.2f * v;
    s += expf(v - mx);
  }
  emax[idx] = mx;
  eden[idx] = s;
}

// ---------------- layer1 aggregation + bias + relu + head-mean ----------------
__global__ __launch_bounds__(256) void k_aggr1(
    const int* __restrict__ offs, const int* __restrict__ eperm,
    const int* __restrict__ srcv, const float* __restrict__ el,
    const float* __restrict__ er, const float* __restrict__ emax,
    const float* __restrict__ eden, const bf16* __restrict__ h1,
    const float* __restrict__ b1, bf16* __restrict__ outm) {
  int dn = blockIdx.x;
  int t = threadIdx.x;
  int head = t >> 5;          // 8 heads x 32 threads
  int jd = (t & 31) << 3;     // 8 contiguous d per thread
  __shared__ float wbuf[32][8];
  __shared__ int sidx[32];
  __shared__ float obuf[2048];
  float acc[8] = {0.f, 0.f, 0.f, 0.f, 0.f, 0.f, 0.f, 0.f};
  int s0 = offs[dn], s1 = offs[dn + 1];
  for (int base = s0; base < s1; base += 32) {
    int rem = s1 - base;
    int cnt = rem < 32 ? rem : 32;
    __syncthreads();
    if (t < cnt * 8) {
      int ec = t >> 3, hh = t & 7;
      int e = eperm[base + ec];
      int sv = srcv[e];
      if (hh == 0) sidx[ec] = sv;
      float v = el[sv * 8 + hh] + er[dn * 8 + hh];
      v = v > 0.f ? v : 0.2f * v;
      float den = eden[dn * 8 + hh];
      wbuf[ec][hh] = den > 0.f ? expf(v - emax[dn * 8 + hh]) / den : 0.f;
    }
    __syncthreads();
    for (int ec = 0; ec < cnt; ++ec) {
      float w = wbuf[ec][head];
      const bf16* hp = h1 + (size_t)sidx[ec] * 2048 + (head << 8) + jd;
      bf16x8 x = *(const bf16x8*)hp;
#pragma unroll
      for (int e2 = 0; e2 < 8; ++e2) acc[e2] += w * (float)x[e2];
    }
  }
  int ob = (head << 8) + jd;
#pragma unroll
  for (int k2 = 0; k2 < 8; ++k2) {
    float v = acc[k2] + b1[ob + k2];
    obuf[ob + k2] = v > 0.f ? v : 0.f;   // relu per head BEFORE mean
  }
  __syncthreads();
  float sum = 0.f;
#pragma unroll
  for (int hh = 0; hh < 8; ++hh) sum += obuf[hh * 256 + t];
  outm[(size_t)dn * 256 + t] = (bf16)(sum * 0.125f);
}

// ---------------- layer2 aggregation + bias (no act) -> d_out ----------------
__global__ __launch_bounds__(128) void k_aggr2(
    const int* __restrict__ offs, const int* __restrict__ eperm,
    const int* __restrict__ srcv, const float* __restrict__ el,
    const float* __restrict__ er, const float* __restrict__ emax,
    const float* __restrict__ eden, const float* __restrict__ h2,
    const float* __restrict__ b2, float* __restrict__ out) {
  int dn = blockIdx.x;
  int t = threadIdx.x;
  __shared__ float wbuf[64];
  __shared__ int sidx[64];
  float acc = 0.f;
  int s0 = offs[dn], s1 = offs[dn + 1];
  float erv = er[dn], mx = emax[dn], den = eden[dn];
  for (int base = s0; base < s1; base += 64) {
    int rem = s1 - base;
    int cnt = rem < 64 ? rem : 64;
    __syncthreads();
    if (t < cnt) {
      int e = eperm[base + t];
      int sv = srcv[e];
      sidx[t] = sv;
      float v = el[sv] + erv;
      v = v > 0.f ? v : 0.2f * v;
      wbuf[t] = den > 0.f ? expf(v - mx) / den : 0.f;
    }
    __syncthreads();
    for (int ec = 0; ec < cnt; ++ec)
      acc += wbuf[ec] * h2[(size_t)sidx[ec] * 128 + t];
  }
  out[(size_t)dn * 128 + t] = acc + b2[t];
}

// ---------------------------------------------------------------------------
extern "C" void kernel_launch(void* const* d_in, const int* in_sizes, int n_in,
                              void* d_out, int out_size, void* d_ws, size_t ws_size,
                              hipStream_t stream) {
  const float* feat = (const float*)d_in[0];
  const float* W1   = (const float*)d_in[1];
  const float* al1  = (const float*)d_in[2];
  const float* ar1  = (const float*)d_in[3];
  const float* b1   = (const float*)d_in[4];
  const float* W2   = (const float*)d_in[5];
  const float* al2  = (const float*)d_in[6];
  const float* ar2  = (const float*)d_in[7];
  const float* b2   = (const float*)d_in[8];
  const int* src0   = (const int*)d_in[9];
  const int* dst0   = (const int*)d_in[10];
  const int* src1   = (const int*)d_in[11];
  const int* dst1   = (const int*)d_in[12];
  float* out = (float*)d_out;

  // opt-in to 128 KiB dynamic LDS for the 256-tile GEMM (host-side, not a
  // stream op -> graph-capture safe). Guarded so it runs once per process.
  static bool s_attr_set = false;
  if (!s_attr_set) {
    hipFuncSetAttribute(reinterpret_cast<const void*>(k_gemm256_bt),
                        hipFuncAttributeMaxDynamicSharedMemorySize, 131072);
    s_attr_set = true;
  }

  // ---- workspace carve ----
  char* w = (char*)d_ws;
  auto alloc = [&](size_t bytes) {
    char* p = w;
    w += (bytes + 255) & ~(size_t)255;
    return p;
  };
  bf16*  featb   = (bf16*)alloc((size_t)M1PAD * K1V * 2);     // 246.4 MB
  bf16*  w1t     = (bf16*)alloc((size_t)HD1V * K1V * 2);      // 8.4 MB
  bf16*  w2t     = (bf16*)alloc((size_t)128 * 256 * 2);
  bf16*  h1      = (bf16*)alloc((size_t)M1PAD * HD1V * 2);    // 246.4 MB
  float* el1     = (float*)alloc((size_t)N_SRC0V * 8 * 4);
  float* er1     = (float*)alloc((size_t)N_DST0V * 8 * 4);
  float* emax1   = (float*)alloc((size_t)N_DST0V * 8 * 4);
  float* eden1   = (float*)alloc((size_t)N_DST0V * 8 * 4);
  bf16*  outm    = (bf16*)alloc((size_t)M2PAD * 256 * 2);
  float* h2      = (float*)alloc((size_t)M2PAD * 128 * 4);
  float* el2     = (float*)alloc((size_t)N_DST0V * 4);
  float* er2     = (float*)alloc((size_t)N_DST1V * 4);
  float* emax2   = (float*)alloc((size_t)N_DST1V * 4);
  float* eden2   = (float*)alloc((size_t)N_DST1V * 4);
  int*   counts1 = (int*)alloc((size_t)N_DST0V * 4);
  int*   offs1   = (int*)alloc((size_t)(N_DST0V + 1) * 4);
  int*   cursor1 = (int*)alloc((size_t)N_DST0V * 4);
  int*   eperm1  = (int*)alloc((size_t)E0V * 4);
  int*   counts2 = (int*)alloc((size_t)N_DST1V * 4);
  int*   offs2   = (int*)alloc((size_t)(N_DST1V + 1) * 4);
  int*   cursor2 = (int*)alloc((size_t)N_DST1V * 4);
  int*   eperm2  = (int*)alloc((size_t)E1V * 4);

  // ---- prep: zero counts, convert feat, zero featb pad rows, transpose W ----
  k_zero<<<(N_DST0V + 255) / 256, 256, 0, stream>>>(counts1, N_DST0V);
  k_zero<<<(N_DST1V + 255) / 256, 256, 0, stream>>>(counts2, N_DST1V);
  {
    long n8 = (long)N_SRC0V * K1V / 8;
    k_convert<<<(unsigned)((n8 + 255) / 256), 256, 0, stream>>>(feat, featb, n8);
    // zero pad rows [N_SRC0V, M1PAD): (160*2048 bf16) = 163840 ints
    int padi = (M1PAD - N_SRC0V) * K1V / 2;
    k_zero<<<(padi + 255) / 256, 256, 0, stream>>>(
        (int*)(featb + (size_t)N_SRC0V * K1V), padi);
  }
  k_transpose_bf16<<<dim3(64, 64), 256, 0, stream>>>(W1, w1t, K1V, HD1V);
  k_transpose_bf16<<<dim3(4, 8), 256, 0, stream>>>(W2, w2t, 256, 128);

  // ---- layer 1 ----
  k_gemm256_bt<<<dim3(HD1V / GBN, M1PAD / GBM), 512, 131072, stream>>>(
      featb, w1t, h1, HD1V, K1V);
  k_el_er1<<<N_SRC0V, 256, 0, stream>>>(h1, al1, ar1, el1, er1, N_DST0V);
  k_hist<<<(E0V + 255) / 256, 256, 0, stream>>>(dst0, E0V, counts1);
  k_scan<<<1, 1024, 0, stream>>>(counts1, N_DST0V, offs1, cursor1);
  k_scatter<<<(E0V + 255) / 256, 256, 0, stream>>>(dst0, E0V, cursor1, eperm1);
  k_stats<<<(N_DST0V * 8 + 255) / 256, 256, 0, stream>>>(offs1, eperm1, src0, el1, er1,
                                                         N_DST0V, 8, emax1, eden1);
  k_aggr1<<<N_DST0V, 256, 0, stream>>>(offs1, eperm1, src0, el1, er1, emax1, eden1,
                                       h1, b1, outm);

  // ---- layer 2 ----
  k_gemm_bt<float><<<dim3(1, M2PAD / BM), 256, 0, stream>>>(outm, w2t, h2, 128, 256);
  k_el_er2<<<M2PAD / 16, 256, 0, stream>>>(h2, al2, ar2, el2, er2, N_DST0V, N_DST1V);
  k_hist<<<(E1V + 255) / 256, 256, 0, stream>>>(dst1, E1V, counts2);
  k_scan<<<1, 1024, 0, stream>>>(counts2, N_DST1V, offs2, cursor2);
  k_scatter<<<(E1V + 255) / 256, 256, 0, stream>>>(dst1, E1V, cursor2, eperm2);
  k_stats<<<(N_DST1V + 255) / 256, 256, 0, stream>>>(offs2, eperm2, src1, el2, er2,
                                                     N_DST1V, 1, emax2, eden2);
  k_aggr2<<<N_DST1V, 128, 0, stream>>>(offs2, eperm2, src1, el2, er2, emax2, eden2,
                                       h2, b2, out);
}

// Round 2
// 1604.234 us; speedup vs baseline: 1.2439x; 1.0561x over previous
//
#include <hip/hip_runtime.h>
#include <hip/hip_bf16.h>

// ---------------------------------------------------------------------------
// 2-layer GAT on MI355X.
// R3 -> R4 changes (GEMM1 only):
//  * BK 64 -> 32, LDS ring of 4 buffers (4 x 32 KiB), prefetch depth 3.
//  * Raw s_barrier + counted inline-asm s_waitcnt vmcnt(8) -- loads stay in
//    flight ACROSS the per-tile barrier (T4). __syncthreads()'s implicit
//    vmcnt(0) drain was the R3 limiter (MfmaUtil stuck at 29.6%).
//  * Last two tiles peeled with vmcnt(4)/vmcnt(0).
//  * sched_barrier(0) fences: after each asm waitcnt (rule #18: compiler
//    hoists register-only MFMA past asm lgkmcnt) and around raw barriers.
//  * LDS stays MFMA-fragment-order (lane-linear) -> zero bank conflicts.
// ---------------------------------------------------------------------------

typedef __bf16 bf16;
typedef bf16 bf16x8 __attribute__((ext_vector_type(8)));
typedef float f32x4 __attribute__((ext_vector_type(4)));

#define N_SRC0V 60000
#define N_DST0V 15000
#define N_DST1V 4000
#define E0V 240000
#define E1V 64000
#define HD1V 2048
#define K1V 2048
#define M1PAD 60160
#define M2PAD 15104

// 128-tile params (GEMM2 only)
#define BM 128
#define BN 128
#define BK 64

// 256-tile params (GEMM1)
#define GBM 256
#define GBN 256
#define GBK 32

__device__ __forceinline__ void gload16(const void* g, void* l) {
  __builtin_amdgcn_global_load_lds(
      (__attribute__((address_space(1))) void*)(g),
      (__attribute__((address_space(3))) void*)(l), 16, 0, 0);
}

// ---------------- feat fp32 -> bf16, 8 elems/thread ----------------
__global__ void k_convert(const float* __restrict__ x, bf16* __restrict__ y, long n8) {
  long i = (long)blockIdx.x * 256 + threadIdx.x;
  if (i >= n8) return;
  const float4* xp = (const float4*)(x + i * 8);
  float4 a = xp[0], b = xp[1];
  bf16x8 o;
  o[0] = (bf16)a.x; o[1] = (bf16)a.y; o[2] = (bf16)a.z; o[3] = (bf16)a.w;
  o[4] = (bf16)b.x; o[5] = (bf16)b.y; o[6] = (bf16)b.z; o[7] = (bf16)b.w;
  *(bf16x8*)(y + i * 8) = o;
}

// ---------------- W[R][C] fp32 -> WT[C][R] bf16 ----------------
__global__ void k_transpose_bf16(const float* __restrict__ W, bf16* __restrict__ WT,
                                 int R, int C) {
  __shared__ float tile[32][33];
  int tx = threadIdx.x & 31, ty = threadIdx.x >> 5;
  int c0 = blockIdx.x * 32, r0 = blockIdx.y * 32;
  for (int i = ty; i < 32; i += 8) {
    int r = r0 + i, c = c0 + tx;
    tile[i][tx] = (r < R && c < C) ? W[(size_t)r * C + c] : 0.f;
  }
  __syncthreads();
  for (int i = ty; i < 32; i += 8) {
    int c = c0 + i, r = r0 + tx;
    if (c < C && r < R) WT[(size_t)c * R + r] = (bf16)tile[tx][i];
  }
}

// ---------------- GEMM1: 256x256 tile, BK=32, ring-4 LDS, 8 waves ----------
// C[M][N] = A[M][K] * BT[N][K]^T, all dims multiples of tile sizes.
// LDS fragment order per buffer: chunk c in [0,1024), seg=c>>6, ln=c&63;
// lane ln of seg holds X[seg*16 + (ln&15)][(ln>>4)*8 .. +7]. All LDS traffic
// is base + lane*16B -> conflict-free, and matches global_load_lds's
// wave-uniform-base + lane*16 requirement exactly.
// Schedule: prefetch depth 3 (12 loads/wave in flight), per K-tile:
//   vmcnt(8) -> tile kt resident (8 newest = tiles kt+1,kt+2 stay in flight)
//   s_barrier (raw: no implicit drain)
//   issue stage(kt+3)        (4 global_load_lds, lands >=2 tiles later)
//   12 ds_read_b128 ; lgkmcnt(0) ; setprio(1) ; 32 MFMA ; setprio(0)
// WAR: stage(kt+3) overwrites buf[(kt-1)&3]; every wave finished its kt-1
// ds_reads (lgkmcnt(0) precedes its MFMAs) before passing iter-kt's barrier.
__global__ __launch_bounds__(512, 2) void k_gemm256_bt(
    const bf16* __restrict__ A, const bf16* __restrict__ BT,
    bf16* __restrict__ C, int N, int K) {
  extern __shared__ char smem_raw[];
  bf16* smem = (bf16*)smem_raw;   // [4][8192 A + 8192 B]
  const int tid = threadIdx.x;
  const int lane = tid & 63;
  const int wv = tid >> 6;        // 0..7
  const int wm = wv >> 2;         // 0..1 -> 128-row half
  const int wn = wv & 3;          // 0..3 -> 64-col quarter
  const int lr = lane & 15, lq = lane >> 4;

  // XCD-aware swizzle (bijective: nwg % 8 == 0 for GEMM1's 8x235 grid)
  int nwg = gridDim.x * gridDim.y;
  int flat = blockIdx.y * gridDim.x + blockIdx.x;
  if ((nwg & 7) == 0) {
    int cpx = nwg >> 3;
    flat = (flat & 7) * cpx + (flat >> 3);
  }
  const int m0 = (flat / gridDim.x) * GBM;
  const int n0 = (flat % gridDim.x) * GBN;

  const f32x4 vzero = {0.f, 0.f, 0.f, 0.f};
  f32x4 acc[8][4];
#pragma unroll
  for (int i = 0; i < 8; ++i)
#pragma unroll
    for (int j = 0; j < 4; ++j) acc[i][j] = vzero;

  // stage one 256x32 A-tile + 256x32 B-tile (fragment order) into buffer b.
  // 4 global_load_lds per thread/wave, issued in fixed program order.
  auto stage = [&](int b, int k0) {
    bf16* sAb = smem + b * 16384;
    bf16* sBb = sAb + 8192;
#pragma unroll
    for (int it = 0; it < 2; ++it) {
      int c = it * 512 + tid;       // 0..1023
      int ln = c & 63;
      int row = (c >> 6) * 16 + (ln & 15);
      int col = (ln >> 4) * 8;
      gload16(A + (size_t)(m0 + row) * K + k0 + col, &sAb[c * 8]);
    }
#pragma unroll
    for (int it = 0; it < 2; ++it) {
      int c = it * 512 + tid;
      int ln = c & 63;
      int row = (c >> 6) * 16 + (ln & 15);
      int col = (ln >> 4) * 8;
      gload16(BT + (size_t)(n0 + row) * K + k0 + col, &sBb[c * 8]);
    }
  };

  const int NT = K / GBK;           // 64 for GEMM1
  stage(0, 0);
  stage(1, GBK);
  stage(2, 2 * GBK);                // 12 loads/wave in flight

  for (int kt = 0; kt < NT; ++kt) {
    const int cb = kt & 3;
    const bf16* sAb = smem + cb * 16384;
    const bf16* sBb = sAb + 8192;

    // counted wait: oldest tile (kt) resident, newer prefetches stay in flight
    if (kt < NT - 2) {
      asm volatile("s_waitcnt vmcnt(8)" ::: "memory");
    } else if (kt == NT - 2) {
      asm volatile("s_waitcnt vmcnt(4)" ::: "memory");
    } else {
      asm volatile("s_waitcnt vmcnt(0)" ::: "memory");
    }
    __builtin_amdgcn_sched_barrier(0);
    __builtin_amdgcn_s_barrier();
    __builtin_amdgcn_sched_barrier(0);

    if (kt + 3 < NT) stage((kt + 3) & 3, (kt + 3) * GBK);  // lands >=2 tiles out

    bf16x8 af[8], bfr[4];
#pragma unroll
    for (int j = 0; j < 4; ++j)
      bfr[j] = *(const bf16x8*)&sBb[((wn * 4 + j) * 64 + lane) * 8];
#pragma unroll
    for (int i = 0; i < 8; ++i)
      af[i] = *(const bf16x8*)&sAb[((wm * 8 + i) * 64 + lane) * 8];
    __builtin_amdgcn_sched_barrier(0);
    asm volatile("s_waitcnt lgkmcnt(0)" ::: "memory");
    __builtin_amdgcn_sched_barrier(0);   // rule #18: keep MFMA below the wait
    __builtin_amdgcn_s_setprio(1);
#pragma unroll
    for (int i = 0; i < 8; ++i)
#pragma unroll
      for (int j = 0; j < 4; ++j)
        acc[i][j] = __builtin_amdgcn_mfma_f32_16x16x32_bf16(af[i], bfr[j], acc[i][j], 0, 0, 0);
    __builtin_amdgcn_s_setprio(0);
    __builtin_amdgcn_sched_barrier(0);
  }

  // epilogue: D row=(lane>>4)*4+reg, col=lane&15  [m89/m91-verified layout]
#pragma unroll
  for (int i = 0; i < 8; ++i)
#pragma unroll
    for (int j = 0; j < 4; ++j) {
      int row = m0 + wm * 128 + i * 16 + lq * 4;
      int col = n0 + wn * 64 + j * 16 + lr;
#pragma unroll
      for (int r = 0; r < 4; ++r)
        C[(size_t)(row + r) * N + col] = (bf16)acc[i][j][r];
    }
}

// ---------------- GEMM2 (small): 128x128 tile, 4 waves 2x2 ------------------
template <typename OutT>
__global__ __launch_bounds__(256) void k_gemm_bt(
    const bf16* __restrict__ A, const bf16* __restrict__ BT,
    OutT* __restrict__ C, int N, int K) {
  __shared__ bf16 sA[BM * BK];
  __shared__ bf16 sB[BN * BK];
  const int tid = threadIdx.x;
  const int lane = tid & 63;
  const int wv = tid >> 6;
  const int wm = wv >> 1, wn = wv & 1;
  const int lr = lane & 15, lq = lane >> 4;
  const int m0 = blockIdx.y * BM;
  const int n0 = blockIdx.x * BN;

  const f32x4 vzero = {0.f, 0.f, 0.f, 0.f};
  f32x4 acc[4][4];
#pragma unroll
  for (int i = 0; i < 4; ++i)
#pragma unroll
    for (int j = 0; j < 4; ++j) acc[i][j] = vzero;

  for (int k0 = 0; k0 < K; k0 += BK) {
#pragma unroll
    for (int it = 0; it < 4; ++it) {
      int c = it * 256 + tid;           // 0..1023
      int seg = c >> 6;                 // wave-uniform (it*4 + wv)
      int ln = c & 63;
      int row = (seg >> 1) * 16 + (ln & 15);
      int col = (seg & 1) * 32 + (ln >> 4) * 8;
      gload16(A + (size_t)(m0 + row) * K + k0 + col, &sA[c * 8]);
      gload16(BT + (size_t)(n0 + row) * K + k0 + col, &sB[c * 8]);
    }
    __syncthreads();
#pragma unroll
    for (int kk = 0; kk < BK; kk += 32) {
      const int kb = kk >> 5;
      bf16x8 af[4], bfr[4];
#pragma unroll
      for (int i = 0; i < 4; ++i)
        af[i] = *(const bf16x8*)&sA[(((wm * 4 + i) * 2 + kb) * 64 + lane) * 8];
#pragma unroll
      for (int j = 0; j < 4; ++j)
        bfr[j] = *(const bf16x8*)&sB[(((wn * 4 + j) * 2 + kb) * 64 + lane) * 8];
#pragma unroll
      for (int i = 0; i < 4; ++i)
#pragma unroll
        for (int j = 0; j < 4; ++j)
          acc[i][j] = __builtin_amdgcn_mfma_f32_16x16x32_bf16(af[i], bfr[j], acc[i][j], 0, 0, 0);
    }
    __syncthreads();
  }
#pragma unroll
  for (int i = 0; i < 4; ++i)
#pragma unroll
    for (int j = 0; j < 4; ++j) {
      int row = m0 + wm * 64 + i * 16 + lq * 4;
      int col = n0 + wn * 64 + j * 16 + lr;
#pragma unroll
      for (int r = 0; r < 4; ++r)
        C[(size_t)(row + r) * N + col] = (OutT)acc[i][j][r];
    }
}

// ---------------- layer1 el/er: h bf16 [row][2048], 8 heads x 256 ----------
__global__ void k_el_er1(const bf16* __restrict__ h, const float* __restrict__ al,
                         const float* __restrict__ ar, float* __restrict__ el,
                         float* __restrict__ er, int n_dst) {
  int row = blockIdx.x;
  int t = threadIdx.x;               // head = t>>5, 32 threads/head, 8 d each
  bf16x8 hv = *(const bf16x8*)(h + (size_t)row * 2048 + t * 8);
  float pl = 0.f, pr = 0.f;
#pragma unroll
  for (int e = 0; e < 8; ++e) {
    float v = (float)hv[e];
    pl += v * al[t * 8 + e];
    pr += v * ar[t * 8 + e];
  }
#pragma unroll
  for (int off = 16; off >= 1; off >>= 1) {
    pl += __shfl_down(pl, off);
    pr += __shfl_down(pr, off);
  }
  if ((t & 31) == 0) {
    el[(size_t)row * 8 + (t >> 5)] = pl;
    if (row < n_dst) er[(size_t)row * 8 + (t >> 5)] = pr;
  }
}

// ---------------- layer2 el/er: h fp32 [row][128], 1 head ----------------
__global__ void k_el_er2(const float* __restrict__ h, const float* __restrict__ al,
                         const float* __restrict__ ar, float* __restrict__ el,
                         float* __restrict__ er, int n_el, int n_dst) {
  int t = threadIdx.x;
  int row = blockIdx.x * 16 + (t >> 4);   // 16 rows/block, 16 threads/row
  int s = t & 15;
  const float* hp = h + (size_t)row * 128 + s * 8;
  float4 a = *(const float4*)hp;
  float4 b = *(const float4*)(hp + 4);
  float pl = a.x * al[s * 8] + a.y * al[s * 8 + 1] + a.z * al[s * 8 + 2] + a.w * al[s * 8 + 3]
           + b.x * al[s * 8 + 4] + b.y * al[s * 8 + 5] + b.z * al[s * 8 + 6] + b.w * al[s * 8 + 7];
  float pr = a.x * ar[s * 8] + a.y * ar[s * 8 + 1] + a.z * ar[s * 8 + 2] + a.w * ar[s * 8 + 3]
           + b.x * ar[s * 8 + 4] + b.y * ar[s * 8 + 5] + b.z * ar[s * 8 + 6] + b.w * ar[s * 8 + 7];
#pragma unroll
  for (int off = 8; off >= 1; off >>= 1) {
    pl += __shfl_down(pl, off);
    pr += __shfl_down(pr, off);
  }
  if (s == 0 && row < n_el) {
    el[row] = pl;
    if (row < n_dst) er[row] = pr;
  }
}

// ---------------- CSR build ----------------
__global__ void k_zero(int* __restrict__ p, int n) {
  int i = blockIdx.x * 256 + threadIdx.x;
  if (i < n) p[i] = 0;
}
__global__ void k_hist(const int* __restrict__ d, int E, int* __restrict__ counts) {
  int e = blockIdx.x * 256 + threadIdx.x;
  if (e < E) atomicAdd(&counts[d[e]], 1);
}
__global__ void k_scan(const int* __restrict__ counts, int n, int* __restrict__ offs,
                       int* __restrict__ cursor) {
  __shared__ int part[1024];
  int t = threadIdx.x;
  int per = (n + 1023) >> 10;
  int b = t * per;
  int e = b + per < n ? b + per : n;
  int s = 0;
  for (int i = b; i < e; ++i) s += counts[i];
  part[t] = s;
  __syncthreads();
  for (int off = 1; off < 1024; off <<= 1) {
    int v = 0;
    if (t >= off) v = part[t - off];
    __syncthreads();
    part[t] += v;
    __syncthreads();
  }
  int run = (t == 0) ? 0 : part[t - 1];
  for (int i = b; i < e; ++i) { offs[i] = run; cursor[i] = run; run += counts[i]; }
  if (t == 1023) offs[n] = run;
}
__global__ void k_scatter(const int* __restrict__ d, int E, int* __restrict__ cursor,
                          int* __restrict__ eperm) {
  int e = blockIdx.x * 256 + threadIdx.x;
  if (e < E) eperm[atomicAdd(&cursor[d[e]], 1)] = e;
}

// ---------------- per-(dst,head) softmax max/denominator ----------------
__global__ void k_stats(const int* __restrict__ offs, const int* __restrict__ eperm,
                        const int* __restrict__ srcv, const float* __restrict__ el,
                        const float* __restrict__ er, int n_dst, int H,
                        float* __restrict__ emax, float* __restrict__ eden) {
  int idx = blockIdx.x * 256 + threadIdx.x;
  if (idx >= n_dst * H) return;
  int dn = idx / H, hh = idx - dn * H;
  int s0 = offs[dn], s1 = offs[dn + 1];
  float erv = er[idx];
  float mx = -1e30f;
  for (int p = s0; p < s1; ++p) {
    float v = el[srcv[eperm[p]] * H + hh] + erv;
    v = v > 0.f ? v : 0.2f * v;
    mx = fmaxf(mx, v);
  }
  if (s1 == s0) mx = 0.f;  // zero in-degree guard (matches isfinite guard)
  float s = 0.f;
  for (int p = s0; p < s1; ++p) {
    float v = el[srcv[eperm[p]] * H + hh] + erv;
    v = v > 0.f ? v : 0.2f * v;
    s += expf(v - mx);
  }
  emax[idx] = mx;
  eden[idx] = s;
}

// ---------------- layer1 aggregation + bias + relu + head-mean ----------------
__global__ __launch_bounds__(256) void k_aggr1(
    const int* __restrict__ offs, const int* __restrict__ eperm,
    const int* __restrict__ srcv, const float* __restrict__ el,
    const float* __restrict__ er, const float* __restrict__ emax,
    const float* __restrict__ eden, const bf16* __restrict__ h1,
    const float* __restrict__ b1, bf16* __restrict__ outm) {
  int dn = blockIdx.x;
  int t = threadIdx.x;
  int head = t >> 5;          // 8 heads x 32 threads
  int jd = (t & 31) << 3;     // 8 contiguous d per thread
  __shared__ float wbuf[32][8];
  __shared__ int sidx[32];
  __shared__ float obuf[2048];
  float acc[8] = {0.f, 0.f, 0.f, 0.f, 0.f, 0.f, 0.f, 0.f};
  int s0 = offs[dn], s1 = offs[dn + 1];
  for (int base = s0; base < s1; base += 32) {
    int rem = s1 - base;
    int cnt = rem < 32 ? rem : 32;
    __syncthreads();
    if (t < cnt * 8) {
      int ec = t >> 3, hh = t & 7;
      int e = eperm[base + ec];
      int sv = srcv[e];
      if (hh == 0) sidx[ec] = sv;
      float v = el[sv * 8 + hh] + er[dn * 8 + hh];
      v = v > 0.f ? v : 0.2f * v;
      float den = eden[dn * 8 + hh];
      wbuf[ec][hh] = den > 0.f ? expf(v - emax[dn * 8 + hh]) / den : 0.f;
    }
    __syncthreads();
    for (int ec = 0; ec < cnt; ++ec) {
      float w = wbuf[ec][head];
      const bf16* hp = h1 + (size_t)sidx[ec] * 2048 + (head << 8) + jd;
      bf16x8 x = *(const bf16x8*)hp;
#pragma unroll
      for (int e2 = 0; e2 < 8; ++e2) acc[e2] += w * (float)x[e2];
    }
  }
  int ob = (head << 8) + jd;
#pragma unroll
  for (int k2 = 0; k2 < 8; ++k2) {
    float v = acc[k2] + b1[ob + k2];
    obuf[ob + k2] = v > 0.f ? v : 0.f;   // relu per head BEFORE mean
  }
  __syncthreads();
  float sum = 0.f;
#pragma unroll
  for (int hh = 0; hh < 8; ++hh) sum += obuf[hh * 256 + t];
  outm[(size_t)dn * 256 + t] = (bf16)(sum * 0.125f);
}

// ---------------- layer2 aggregation + bias (no act) -> d_out ----------------
__global__ __launch_bounds__(128) void k_aggr2(
    const int* __restrict__ offs, const int* __restrict__ eperm,
    const int* __restrict__ srcv, const float* __restrict__ el,
    const float* __restrict__ er, const float* __restrict__ emax,
    const float* __restrict__ eden, const float* __restrict__ h2,
    const float* __restrict__ b2, float* __restrict__ out) {
  int dn = blockIdx.x;
  int t = threadIdx.x;
  __shared__ float wbuf[64];
  __shared__ int sidx[64];
  float acc = 0.f;
  int s0 = offs[dn], s1 = offs[dn + 1];
  float erv = er[dn], mx = emax[dn], den = eden[dn];
  for (int base = s0; base < s1; base += 64) {
    int rem = s1 - base;
    int cnt = rem < 64 ? rem : 64;
    __syncthreads();
    if (t < cnt) {
      int e = eperm[base + t];
      int sv = srcv[e];
      sidx[t] = sv;
      float v = el[sv] + erv;
      v = v > 0.f ? v : 0.2f * v;
      wbuf[t] = den > 0.f ? expf(v - mx) / den : 0.f;
    }
    __syncthreads();
    for (int ec = 0; ec < cnt; ++ec)
      acc += wbuf[ec] * h2[(size_t)sidx[ec] * 128 + t];
  }
  out[(size_t)dn * 128 + t] = acc + b2[t];
}

// ---------------------------------------------------------------------------
extern "C" void kernel_launch(void* const* d_in, const int* in_sizes, int n_in,
                              void* d_out, int out_size, void* d_ws, size_t ws_size,
                              hipStream_t stream) {
  const float* feat = (const float*)d_in[0];
  const float* W1   = (const float*)d_in[1];
  const float* al1  = (const float*)d_in[2];
  const float* ar1  = (const float*)d_in[3];
  const float* b1   = (const float*)d_in[4];
  const float* W2   = (const float*)d_in[5];
  const float* al2  = (const float*)d_in[6];
  const float* ar2  = (const float*)d_in[7];
  const float* b2   = (const float*)d_in[8];
  const int* src0   = (const int*)d_in[9];
  const int* dst0   = (const int*)d_in[10];
  const int* src1   = (const int*)d_in[11];
  const int* dst1   = (const int*)d_in[12];
  float* out = (float*)d_out;

  // opt-in to 128 KiB dynamic LDS for the 256-tile GEMM (host-side, not a
  // stream op -> graph-capture safe). Guarded so it runs once per process.
  static bool s_attr_set = false;
  if (!s_attr_set) {
    hipFuncSetAttribute(reinterpret_cast<const void*>(k_gemm256_bt),
                        hipFuncAttributeMaxDynamicSharedMemorySize, 131072);
    s_attr_set = true;
  }

  // ---- workspace carve ----
  char* w = (char*)d_ws;
  auto alloc = [&](size_t bytes) {
    char* p = w;
    w += (bytes + 255) & ~(size_t)255;
    return p;
  };
  bf16*  featb   = (bf16*)alloc((size_t)M1PAD * K1V * 2);     // 246.4 MB
  bf16*  w1t     = (bf16*)alloc((size_t)HD1V * K1V * 2);      // 8.4 MB
  bf16*  w2t     = (bf16*)alloc((size_t)128 * 256 * 2);
  bf16*  h1      = (bf16*)alloc((size_t)M1PAD * HD1V * 2);    // 246.4 MB
  float* el1     = (float*)alloc((size_t)N_SRC0V * 8 * 4);
  float* er1     = (float*)alloc((size_t)N_DST0V * 8 * 4);
  float* emax1   = (float*)alloc((size_t)N_DST0V * 8 * 4);
  float* eden1   = (float*)alloc((size_t)N_DST0V * 8 * 4);
  bf16*  outm    = (bf16*)alloc((size_t)M2PAD * 256 * 2);
  float* h2      = (float*)alloc((size_t)M2PAD * 128 * 4);
  float* el2     = (float*)alloc((size_t)N_DST0V * 4);
  float* er2     = (float*)alloc((size_t)N_DST1V * 4);
  float* emax2   = (float*)alloc((size_t)N_DST1V * 4);
  float* eden2   = (float*)alloc((size_t)N_DST1V * 4);
  int*   counts1 = (int*)alloc((size_t)N_DST0V * 4);
  int*   offs1   = (int*)alloc((size_t)(N_DST0V + 1) * 4);
  int*   cursor1 = (int*)alloc((size_t)N_DST0V * 4);
  int*   eperm1  = (int*)alloc((size_t)E0V * 4);
  int*   counts2 = (int*)alloc((size_t)N_DST1V * 4);
  int*   offs2   = (int*)alloc((size_t)(N_DST1V + 1) * 4);
  int*   cursor2 = (int*)alloc((size_t)N_DST1V * 4);
  int*   eperm2  = (int*)alloc((size_t)E1V * 4);

  // ---- prep: zero counts, convert feat, zero featb pad rows, transpose W ----
  k_zero<<<(N_DST0V + 255) / 256, 256, 0, stream>>>(counts1, N_DST0V);
  k_zero<<<(N_DST1V + 255) / 256, 256, 0, stream>>>(counts2, N_DST1V);
  {
    long n8 = (long)N_SRC0V * K1V / 8;
    k_convert<<<(unsigned)((n8 + 255) / 256), 256, 0, stream>>>(feat, featb, n8);
    // zero pad rows [N_SRC0V, M1PAD)
    int padi = (M1PAD - N_SRC0V) * K1V / 2;
    k_zero<<<(padi + 255) / 256, 256, 0, stream>>>(
        (int*)(featb + (size_t)N_SRC0V * K1V), padi);
  }
  k_transpose_bf16<<<dim3(64, 64), 256, 0, stream>>>(W1, w1t, K1V, HD1V);
  k_transpose_bf16<<<dim3(4, 8), 256, 0, stream>>>(W2, w2t, 256, 128);

  // ---- layer 1 ----
  k_gemm256_bt<<<dim3(HD1V / GBN, M1PAD / GBM), 512, 131072, stream>>>(
      featb, w1t, h1, HD1V, K1V);
  k_el_er1<<<N_SRC0V, 256, 0, stream>>>(h1, al1, ar1, el1, er1, N_DST0V);
  k_hist<<<(E0V + 255) / 256, 256, 0, stream>>>(dst0, E0V, counts1);
  k_scan<<<1, 1024, 0, stream>>>(counts1, N_DST0V, offs1, cursor1);
  k_scatter<<<(E0V + 255) / 256, 256, 0, stream>>>(dst0, E0V, cursor1, eperm1);
  k_stats<<<(N_DST0V * 8 + 255) / 256, 256, 0, stream>>>(offs1, eperm1, src0, el1, er1,
                                                         N_DST0V, 8, emax1, eden1);
  k_aggr1<<<N_DST0V, 256, 0, stream>>>(offs1, eperm1, src0, el1, er1, emax1, eden1,
                                       h1, b1, outm);

  // ---- layer 2 ----
  k_gemm_bt<float><<<dim3(1, M2PAD / BM), 256, 0, stream>>>(outm, w2t, h2, 128, 256);
  k_el_er2<<<M2PAD / 16, 256, 0, stream>>>(h2, al2, ar2, el2, er2, N_DST0V, N_DST1V);
  k_hist<<<(E1V + 255) / 256, 256, 0, stream>>>(dst1, E1V, counts2);
  k_scan<<<1, 1024, 0, stream>>>(counts2, N_DST1V, offs2, cursor2);
  k_scatter<<<(E1V + 255) / 256, 256, 0, stream>>>(dst1, E1V, cursor2, eperm2);
  k_stats<<<(N_DST1V + 255) / 256, 256, 0, stream>>>(offs2, eperm2, src1, el2, er2,
                                                     N_DST1V, 1, emax2, eden2);
  k_aggr2<<<N_DST1V, 128, 0, stream>>>(offs2, eperm2, src1, el2, er2, emax2, eden2,
                                       h2, b2, out);
}

// Round 4
// 1603.933 us; speedup vs baseline: 1.2441x; 1.0002x over previous
//
#include <hip/hip_runtime.h>
#include <hip/hip_bf16.h>

// ---------------------------------------------------------------------------
// 2-layer GAT on MI355X.
// R5 -> R6 changes (GEMM1 only):
//  * Same register-double-buffered pipeline as R5 (ds_reads for tile kt+1
//    issued before MFMA of tile kt), but with MINIMAL manual fencing:
//    - dropped manual s_waitcnt lgkmcnt(12): fragment loads are plain C++
//      LDS reads, the compiler inserts the exact counted lgkmcnt itself
//      (m97/r109: its ds_read->MFMA waits are near-optimal; m141: heavy
//      sched_barrier pinning regresses / risks pathological codegen).
//    - kept: counted vmcnt gates + raw s_barrier (compiler can't derive
//      cross-wave residency), one sched_barrier(0) after each barrier so
//      ds_reads (which read other waves' chunks) can't hoist above it.
//  * Everything else (ring-4 LDS, depth-3 staging, setprio, fragment-order
//    LDS -> 0 bank conflicts, XCD swizzle) unchanged from R4/R5.
// ---------------------------------------------------------------------------

typedef __bf16 bf16;
typedef bf16 bf16x8 __attribute__((ext_vector_type(8)));
typedef float f32x4 __attribute__((ext_vector_type(4)));

#define N_SRC0V 60000
#define N_DST0V 15000
#define N_DST1V 4000
#define E0V 240000
#define E1V 64000
#define HD1V 2048
#define K1V 2048
#define M1PAD 60160
#define M2PAD 15104

// 128-tile params (GEMM2 only)
#define BM 128
#define BN 128
#define BK 64

// 256-tile params (GEMM1)
#define GBM 256
#define GBN 256
#define GBK 32

__device__ __forceinline__ void gload16(const void* g, void* l) {
  __builtin_amdgcn_global_load_lds(
      (__attribute__((address_space(1))) void*)(g),
      (__attribute__((address_space(3))) void*)(l), 16, 0, 0);
}

// ---------------- feat fp32 -> bf16, 8 elems/thread ----------------
__global__ void k_convert(const float* __restrict__ x, bf16* __restrict__ y, long n8) {
  long i = (long)blockIdx.x * 256 + threadIdx.x;
  if (i >= n8) return;
  const float4* xp = (const float4*)(x + i * 8);
  float4 a = xp[0], b = xp[1];
  bf16x8 o;
  o[0] = (bf16)a.x; o[1] = (bf16)a.y; o[2] = (bf16)a.z; o[3] = (bf16)a.w;
  o[4] = (bf16)b.x; o[5] = (bf16)b.y; o[6] = (bf16)b.z; o[7] = (bf16)b.w;
  *(bf16x8*)(y + i * 8) = o;
}

// ---------------- W[R][C] fp32 -> WT[C][R] bf16 ----------------
__global__ void k_transpose_bf16(const float* __restrict__ W, bf16* __restrict__ WT,
                                 int R, int C) {
  __shared__ float tile[32][33];
  int tx = threadIdx.x & 31, ty = threadIdx.x >> 5;
  int c0 = blockIdx.x * 32, r0 = blockIdx.y * 32;
  for (int i = ty; i < 32; i += 8) {
    int r = r0 + i, c = c0 + tx;
    tile[i][tx] = (r < R && c < C) ? W[(size_t)r * C + c] : 0.f;
  }
  __syncthreads();
  for (int i = ty; i < 32; i += 8) {
    int c = c0 + i, r = r0 + tx;
    if (c < C && r < R) WT[(size_t)c * R + r] = (bf16)tile[tx][i];
  }
}

// ---------------- GEMM1: 256x256 tile, BK=32, ring-4 LDS, 8 waves ----------
// C[M][N] = A[M][K] * BT[N][K]^T, all dims multiples of tile sizes.
// LDS fragment order per buffer: chunk c in [0,1024), seg=c>>6, ln=c&63;
// lane ln of seg holds X[seg*16 + (ln&15)][(ln>>4)*8 .. +7].
// Steady-state per K-tile kt (frags for kt already in regs, set CUR):
//   s_waitcnt vmcnt(4)   -> tile kt+1 resident (stages kt+2 stay in flight)
//   s_barrier            -> raw, no drain; sched_barrier(0) keeps ds_reads
//                           (which read other waves' chunks) below it
//   12x ds_read frags(kt+1) -> set NXT   (compiler-counted lgkm gate lets
//                                         these overlap the MFMAs below)
//   stage(kt+3)          -> 4 global_load_lds, lands >=2 tiles out
//   setprio(1); 32 MFMA with set CUR; setprio(0)
// WAR: every frag reg is consumed by an MFMA in its sub-iter, so all reads
// of buf[kt-1] completed (compiler lgkm gate) before the wave reaches the
// next barrier, which precedes the stage() that overwrites buf[kt-1].
__global__ __launch_bounds__(512, 2) void k_gemm256_bt(
    const bf16* __restrict__ A, const bf16* __restrict__ BT,
    bf16* __restrict__ C, int N, int K) {
  extern __shared__ char smem_raw[];
  bf16* smem = (bf16*)smem_raw;   // [4][8192 A + 8192 B]
  const int tid = threadIdx.x;
  const int lane = tid & 63;
  const int wv = tid >> 6;        // 0..7
  const int wm = wv >> 2;         // 0..1 -> 128-row half
  const int wn = wv & 3;          // 0..3 -> 64-col quarter
  const int lr = lane & 15, lq = lane >> 4;

  // XCD-aware swizzle (bijective: nwg % 8 == 0 for GEMM1's 8x235 grid)
  int nwg = gridDim.x * gridDim.y;
  int flat = blockIdx.y * gridDim.x + blockIdx.x;
  if ((nwg & 7) == 0) {
    int cpx = nwg >> 3;
    flat = (flat & 7) * cpx + (flat >> 3);
  }
  const int m0 = (flat / gridDim.x) * GBM;
  const int n0 = (flat % gridDim.x) * GBN;

  const f32x4 vzero = {0.f, 0.f, 0.f, 0.f};
  f32x4 acc[8][4];
#pragma unroll
  for (int i = 0; i < 8; ++i)
#pragma unroll
    for (int j = 0; j < 4; ++j) acc[i][j] = vzero;

  // stage one 256x32 A-tile + 256x32 B-tile (fragment order) into buffer b.
  auto stage = [&](int b, int k0) {
    bf16* sAb = smem + b * 16384;
    bf16* sBb = sAb + 8192;
#pragma unroll
    for (int it = 0; it < 2; ++it) {
      int c = it * 512 + tid;       // 0..1023
      int ln = c & 63;
      int row = (c >> 6) * 16 + (ln & 15);
      int col = (ln >> 4) * 8;
      gload16(A + (size_t)(m0 + row) * K + k0 + col, &sAb[c * 8]);
    }
#pragma unroll
    for (int it = 0; it < 2; ++it) {
      int c = it * 512 + tid;
      int ln = c & 63;
      int row = (c >> 6) * 16 + (ln & 15);
      int col = (ln >> 4) * 8;
      gload16(BT + (size_t)(n0 + row) * K + k0 + col, &sBb[c * 8]);
    }
  };

  // LDS -> register fragments for one buffer (12x ds_read_b128)
  auto ldfrag = [&](int b, bf16x8* af, bf16x8* bf) {
    const bf16* sAb = smem + b * 16384;
    const bf16* sBb = sAb + 8192;
#pragma unroll
    for (int j = 0; j < 4; ++j)
      bf[j] = *(const bf16x8*)&sBb[((wn * 4 + j) * 64 + lane) * 8];
#pragma unroll
    for (int i = 0; i < 8; ++i)
      af[i] = *(const bf16x8*)&sAb[((wm * 8 + i) * 64 + lane) * 8];
  };

  const int NT = K / GBK;           // 64 for GEMM1 (even)
  stage(0, 0);
  stage(1, GBK);
  stage(2, 2 * GBK);                // 12 loads/wave in flight

  asm volatile("s_waitcnt vmcnt(8)" ::: "memory");   // tile 0 resident
  __builtin_amdgcn_s_barrier();
  __builtin_amdgcn_sched_barrier(0);

  bf16x8 afA[8], bfA[4], afB[8], bfB[4];
  ldfrag(0, afA, bfA);              // frags(0) -> set A

  for (int kt = 0; kt < NT; kt += 2) {
    // ---- sub-iter 0: compute kt (set A), read kt+1 -> set B ----
    if (kt + 2 < NT) asm volatile("s_waitcnt vmcnt(4)" ::: "memory");
    else             asm volatile("s_waitcnt vmcnt(0)" ::: "memory");
    __builtin_amdgcn_s_barrier();
    __builtin_amdgcn_sched_barrier(0);
    ldfrag((kt + 1) & 3, afB, bfB);
    if (kt + 3 < NT) stage((kt + 3) & 3, (kt + 3) * GBK);
    __builtin_amdgcn_s_setprio(1);
#pragma unroll
    for (int i = 0; i < 8; ++i)
#pragma unroll
      for (int j = 0; j < 4; ++j)
        acc[i][j] = __builtin_amdgcn_mfma_f32_16x16x32_bf16(afA[i], bfA[j], acc[i][j], 0, 0, 0);
    __builtin_amdgcn_s_setprio(0);

    // ---- sub-iter 1: compute kt+1 (set B), read kt+2 -> set A ----
    if (kt + 2 < NT) {
      asm volatile("s_waitcnt vmcnt(4)" ::: "memory");
      __builtin_amdgcn_s_barrier();
      __builtin_amdgcn_sched_barrier(0);
      ldfrag((kt + 2) & 3, afA, bfA);
      if (kt + 4 < NT) stage((kt + 4) & 3, (kt + 4) * GBK);
    }
    __builtin_amdgcn_s_setprio(1);
#pragma unroll
    for (int i = 0; i < 8; ++i)
#pragma unroll
      for (int j = 0; j < 4; ++j)
        acc[i][j] = __builtin_amdgcn_mfma_f32_16x16x32_bf16(afB[i], bfB[j], acc[i][j], 0, 0, 0);
    __builtin_amdgcn_s_setprio(0);
  }

  // epilogue: D row=(lane>>4)*4+reg, col=lane&15  [m89/m91-verified layout]
#pragma unroll
  for (int i = 0; i < 8; ++i)
#pragma unroll
    for (int j = 0; j < 4; ++j) {
      int row = m0 + wm * 128 + i * 16 + lq * 4;
      int col = n0 + wn * 64 + j * 16 + lr;
#pragma unroll
      for (int r = 0; r < 4; ++r)
        C[(size_t)(row + r) * N + col] = (bf16)acc[i][j][r];
    }
}

// ---------------- GEMM2 (small): 128x128 tile, 4 waves 2x2 ------------------
template <typename OutT>
__global__ __launch_bounds__(256) void k_gemm_bt(
    const bf16* __restrict__ A, const bf16* __restrict__ BT,
    OutT* __restrict__ C, int N, int K) {
  __shared__ bf16 sA[BM * BK];
  __shared__ bf16 sB[BN * BK];
  const int tid = threadIdx.x;
  const int lane = tid & 63;
  const int wv = tid >> 6;
  const int wm = wv >> 1, wn = wv & 1;
  const int lr = lane & 15, lq = lane >> 4;
  const int m0 = blockIdx.y * BM;
  const int n0 = blockIdx.x * BN;

  const f32x4 vzero = {0.f, 0.f, 0.f, 0.f};
  f32x4 acc[4][4];
#pragma unroll
  for (int i = 0; i < 4; ++i)
#pragma unroll
    for (int j = 0; j < 4; ++j) acc[i][j] = vzero;

  for (int k0 = 0; k0 < K; k0 += BK) {
#pragma unroll
    for (int it = 0; it < 4; ++it) {
      int c = it * 256 + tid;           // 0..1023
      int seg = c >> 6;                 // wave-uniform (it*4 + wv)
      int ln = c & 63;
      int row = (seg >> 1) * 16 + (ln & 15);
      int col = (seg & 1) * 32 + (ln >> 4) * 8;
      gload16(A + (size_t)(m0 + row) * K + k0 + col, &sA[c * 8]);
      gload16(BT + (size_t)(n0 + row) * K + k0 + col, &sB[c * 8]);
    }
    __syncthreads();
#pragma unroll
    for (int kk = 0; kk < BK; kk += 32) {
      const int kb = kk >> 5;
      bf16x8 af[4], bfr[4];
#pragma unroll
      for (int i = 0; i < 4; ++i)
        af[i] = *(const bf16x8*)&sA[(((wm * 4 + i) * 2 + kb) * 64 + lane) * 8];
#pragma unroll
      for (int j = 0; j < 4; ++j)
        bfr[j] = *(const bf16x8*)&sB[(((wn * 4 + j) * 2 + kb) * 64 + lane) * 8];
#pragma unroll
      for (int i = 0; i < 4; ++i)
#pragma unroll
        for (int j = 0; j < 4; ++j)
          acc[i][j] = __builtin_amdgcn_mfma_f32_16x16x32_bf16(af[i], bfr[j], acc[i][j], 0, 0, 0);
    }
    __syncthreads();
  }
#pragma unroll
  for (int i = 0; i < 4; ++i)
#pragma unroll
    for (int j = 0; j < 4; ++j) {
      int row = m0 + wm * 64 + i * 16 + lq * 4;
      int col = n0 + wn * 64 + j * 16 + lr;
#pragma unroll
      for (int r = 0; r < 4; ++r)
        C[(size_t)(row + r) * N + col] = (OutT)acc[i][j][r];
    }
}

// ---------------- layer1 el/er: h bf16 [row][2048], 8 heads x 256 ----------
__global__ void k_el_er1(const bf16* __restrict__ h, const float* __restrict__ al,
                         const float* __restrict__ ar, float* __restrict__ el,
                         float* __restrict__ er, int n_dst) {
  int row = blockIdx.x;
  int t = threadIdx.x;               // head = t>>5, 32 threads/head, 8 d each
  bf16x8 hv = *(const bf16x8*)(h + (size_t)row * 2048 + t * 8);
  float pl = 0.f, pr = 0.f;
#pragma unroll
  for (int e = 0; e < 8; ++e) {
    float v = (float)hv[e];
    pl += v * al[t * 8 + e];
    pr += v * ar[t * 8 + e];
  }
#pragma unroll
  for (int off = 16; off >= 1; off >>= 1) {
    pl += __shfl_down(pl, off);
    pr += __shfl_down(pr, off);
  }
  if ((t & 31) == 0) {
    el[(size_t)row * 8 + (t >> 5)] = pl;
    if (row < n_dst) er[(size_t)row * 8 + (t >> 5)] = pr;
  }
}

// ---------------- layer2 el/er: h fp32 [row][128], 1 head ----------------
__global__ void k_el_er2(const float* __restrict__ h, const float* __restrict__ al,
                         const float* __restrict__ ar, float* __restrict__ el,
                         float* __restrict__ er, int n_el, int n_dst) {
  int t = threadIdx.x;
  int row = blockIdx.x * 16 + (t >> 4);   // 16 rows/block, 16 threads/row
  int s = t & 15;
  const float* hp = h + (size_t)row * 128 + s * 8;
  float4 a = *(const float4*)hp;
  float4 b = *(const float4*)(hp + 4);
  float pl = a.x * al[s * 8] + a.y * al[s * 8 + 1] + a.z * al[s * 8 + 2] + a.w * al[s * 8 + 3]
           + b.x * al[s * 8 + 4] + b.y * al[s * 8 + 5] + b.z * al[s * 8 + 6] + b.w * al[s * 8 + 7];
  float pr = a.x * ar[s * 8] + a.y * ar[s * 8 + 1] + a.z * ar[s * 8 + 2] + a.w * ar[s * 8 + 3]
           + b.x * ar[s * 8 + 4] + b.y * ar[s * 8 + 5] + b.z * ar[s * 8 + 6] + b.w * ar[s * 8 + 7];
#pragma unroll
  for (int off = 8; off >= 1; off >>= 1) {
    pl += __shfl_down(pl, off);
    pr += __shfl_down(pr, off);
  }
  if (s == 0 && row < n_el) {
    el[row] = pl;
    if (row < n_dst) er[row] = pr;
  }
}

// ---------------- CSR build ----------------
__global__ void k_zero(int* __restrict__ p, int n) {
  int i = blockIdx.x * 256 + threadIdx.x;
  if (i < n) p[i] = 0;
}
__global__ void k_hist(const int* __restrict__ d, int E, int* __restrict__ counts) {
  int e = blockIdx.x * 256 + threadIdx.x;
  if (e < E) atomicAdd(&counts[d[e]], 1);
}
__global__ void k_scan(const int* __restrict__ counts, int n, int* __restrict__ offs,
                       int* __restrict__ cursor) {
  __shared__ int part[1024];
  int t = threadIdx.x;
  int per = (n + 1023) >> 10;
  int b = t * per;
  int e = b + per < n ? b + per : n;
  int s = 0;
  for (int i = b; i < e; ++i) s += counts[i];
  part[t] = s;
  __syncthreads();
  for (int off = 1; off < 1024; off <<= 1) {
    int v = 0;
    if (t >= off) v = part[t - off];
    __syncthreads();
    part[t] += v;
    __syncthreads();
  }
  int run = (t == 0) ? 0 : part[t - 1];
  for (int i = b; i < e; ++i) { offs[i] = run; cursor[i] = run; run += counts[i]; }
  if (t == 1023) offs[n] = run;
}
__global__ void k_scatter(const int* __restrict__ d, int E, int* __restrict__ cursor,
                          int* __restrict__ eperm) {
  int e = blockIdx.x * 256 + threadIdx.x;
  if (e < E) eperm[atomicAdd(&cursor[d[e]], 1)] = e;
}

// ---------------- per-(dst,head) softmax max/denominator ----------------
__global__ void k_stats(const int* __restrict__ offs, const int* __restrict__ eperm,
                        const int* __restrict__ srcv, const float* __restrict__ el,
                        const float* __restrict__ er, int n_dst, int H,
                        float* __restrict__ emax, float* __restrict__ eden) {
  int idx = blockIdx.x * 256 + threadIdx.x;
  if (idx >= n_dst * H) return;
  int dn = idx / H, hh = idx - dn * H;
  int s0 = offs[dn], s1 = offs[dn + 1];
  float erv = er[idx];
  float mx = -1e30f;
  for (int p = s0; p < s1; ++p) {
    float v = el[srcv[eperm[p]] * H + hh] + erv;
    v = v > 0.f ? v : 0.2f * v;
    mx = fmaxf(mx, v);
  }
  if (s1 == s0) mx = 0.f;  // zero in-degree guard (matches isfinite guard)
  float s = 0.f;
  for (int p = s0; p < s1; ++p) {
    float v = el[srcv[eperm[p]] * H + hh] + erv;
    v = v > 0.f ? v : 0.2f * v;
    s += expf(v - mx);
  }
  emax[idx] = mx;
  eden[idx] = s;
}

// ---------------- layer1 aggregation + bias + relu + head-mean ----------------
__global__ __launch_bounds__(256) void k_aggr1(
    const int* __restrict__ offs, const int* __restrict__ eperm,
    const int* __restrict__ srcv, const float* __restrict__ el,
    const float* __restrict__ er, const float* __restrict__ emax,
    const float* __restrict__ eden, const bf16* __restrict__ h1,
    const float* __restrict__ b1, bf16* __restrict__ outm) {
  int dn = blockIdx.x;
  int t = threadIdx.x;
  int head = t >> 5;          // 8 heads x 32 threads
  int jd = (t & 31) << 3;     // 8 contiguous d per thread
  __shared__ float wbuf[32][8];
  __shared__ int sidx[32];
  __shared__ float obuf[2048];
  float acc[8] = {0.f, 0.f, 0.f, 0.f, 0.f, 0.f, 0.f, 0.f};
  int s0 = offs[dn], s1 = offs[dn + 1];
  for (int base = s0; base < s1; base += 32) {
    int rem = s1 - base;
    int cnt = rem < 32 ? rem : 32;
    __syncthreads();
    if (t < cnt * 8) {
      int ec = t >> 3, hh = t & 7;
      int e = eperm[base + ec];
      int sv = srcv[e];
      if (hh == 0) sidx[ec] = sv;
      float v = el[sv * 8 + hh] + er[dn * 8 + hh];
      v = v > 0.f ? v : 0.2f * v;
      float den = eden[dn * 8 + hh];
      wbuf[ec][hh] = den > 0.f ? expf(v - emax[dn * 8 + hh]) / den : 0.f;
    }
    __syncthreads();
    for (int ec = 0; ec < cnt; ++ec) {
      float w = wbuf[ec][head];
      const bf16* hp = h1 + (size_t)sidx[ec] * 2048 + (head << 8) + jd;
      bf16x8 x = *(const bf16x8*)hp;
#pragma unroll
      for (int e2 = 0; e2 < 8; ++e2) acc[e2] += w * (float)x[e2];
    }
  }
  int ob = (head << 8) + jd;
#pragma unroll
  for (int k2 = 0; k2 < 8; ++k2) {
    float v = acc[k2] + b1[ob + k2];
    obuf[ob + k2] = v > 0.f ? v : 0.f;   // relu per head BEFORE mean
  }
  __syncthreads();
  float sum = 0.f;
#pragma unroll
  for (int hh = 0; hh < 8; ++hh) sum += obuf[hh * 256 + t];
  outm[(size_t)dn * 256 + t] = (bf16)(sum * 0.125f);
}

// ---------------- layer2 aggregation + bias (no act) -> d_out ----------------
__global__ __launch_bounds__(128) void k_aggr2(
    const int* __restrict__ offs, const int* __restrict__ eperm,
    const int* __restrict__ srcv, const float* __restrict__ el,
    const float* __restrict__ er, const float* __restrict__ emax,
    const float* __restrict__ eden, const float* __restrict__ h2,
    const float* __restrict__ b2, float* __restrict__ out) {
  int dn = blockIdx.x;
  int t = threadIdx.x;
  __shared__ float wbuf[64];
  __shared__ int sidx[64];
  float acc = 0.f;
  int s0 = offs[dn], s1 = offs[dn + 1];
  float erv = er[dn], mx = emax[dn], den = eden[dn];
  for (int base = s0; base < s1; base += 64) {
    int rem = s1 - base;
    int cnt = rem < 64 ? rem : 64;
    __syncthreads();
    if (t < cnt) {
      int e = eperm[base + t];
      int sv = srcv[e];
      sidx[t] = sv;
      float v = el[sv] + erv;
      v = v > 0.f ? v : 0.2f * v;
      wbuf[t] = den > 0.f ? expf(v - mx) / den : 0.f;
    }
    __syncthreads();
    for (int ec = 0; ec < cnt; ++ec)
      acc += wbuf[ec] * h2[(size_t)sidx[ec] * 128 + t];
  }
  out[(size_t)dn * 128 + t] = acc + b2[t];
}

// ---------------------------------------------------------------------------
extern "C" void kernel_launch(void* const* d_in, const int* in_sizes, int n_in,
                              void* d_out, int out_size, void* d_ws, size_t ws_size,
                              hipStream_t stream) {
  const float* feat = (const float*)d_in[0];
  const float* W1   = (const float*)d_in[1];
  const float* al1  = (const float*)d_in[2];
  const float* ar1  = (const float*)d_in[3];
  const float* b1   = (const float*)d_in[4];
  const float* W2   = (const float*)d_in[5];
  const float* al2  = (const float*)d_in[6];
  const float* ar2  = (const float*)d_in[7];
  const float* b2   = (const float*)d_in[8];
  const int* src0   = (const int*)d_in[9];
  const int* dst0   = (const int*)d_in[10];
  const int* src1   = (const int*)d_in[11];
  const int* dst1   = (const int*)d_in[12];
  float* out = (float*)d_out;

  // opt-in to 128 KiB dynamic LDS for the 256-tile GEMM (host-side, not a
  // stream op -> graph-capture safe). Guarded so it runs once per process.
  static bool s_attr_set = false;
  if (!s_attr_set) {
    hipFuncSetAttribute(reinterpret_cast<const void*>(k_gemm256_bt),
                        hipFuncAttributeMaxDynamicSharedMemorySize, 131072);
    s_attr_set = true;
  }

  // ---- workspace carve ----
  char* w = (char*)d_ws;
  auto alloc = [&](size_t bytes) {
    char* p = w;
    w += (bytes + 255) & ~(size_t)255;
    return p;
  };
  bf16*  featb   = (bf16*)alloc((size_t)M1PAD * K1V * 2);     // 246.4 MB
  bf16*  w1t     = (bf16*)alloc((size_t)HD1V * K1V * 2);      // 8.4 MB
  bf16*  w2t     = (bf16*)alloc((size_t)128 * 256 * 2);
  bf16*  h1      = (bf16*)alloc((size_t)M1PAD * HD1V * 2);    // 246.4 MB
  float* el1     = (float*)alloc((size_t)N_SRC0V * 8 * 4);
  float* er1     = (float*)alloc((size_t)N_DST0V * 8 * 4);
  float* emax1   = (float*)alloc((size_t)N_DST0V * 8 * 4);
  float* eden1   = (float*)alloc((size_t)N_DST0V * 8 * 4);
  bf16*  outm    = (bf16*)alloc((size_t)M2PAD * 256 * 2);
  float* h2      = (float*)alloc((size_t)M2PAD * 128 * 4);
  float* el2     = (float*)alloc((size_t)N_DST0V * 4);
  float* er2     = (float*)alloc((size_t)N_DST1V * 4);
  float* emax2   = (float*)alloc((size_t)N_DST1V * 4);
  float* eden2   = (float*)alloc((size_t)N_DST1V * 4);
  int*   counts1 = (int*)alloc((size_t)N_DST0V * 4);
  int*   offs1   = (int*)alloc((size_t)(N_DST0V + 1) * 4);
  int*   cursor1 = (int*)alloc((size_t)N_DST0V * 4);
  int*   eperm1  = (int*)alloc((size_t)E0V * 4);
  int*   counts2 = (int*)alloc((size_t)N_DST1V * 4);
  int*   offs2   = (int*)alloc((size_t)(N_DST1V + 1) * 4);
  int*   cursor2 = (int*)alloc((size_t)N_DST1V * 4);
  int*   eperm2  = (int*)alloc((size_t)E1V * 4);

  // ---- prep: zero counts, convert feat, zero featb pad rows, transpose W ----
  k_zero<<<(N_DST0V + 255) / 256, 256, 0, stream>>>(counts1, N_DST0V);
  k_zero<<<(N_DST1V + 255) / 256, 256, 0, stream>>>(counts2, N_DST1V);
  {
    long n8 = (long)N_SRC0V * K1V / 8;
    k_convert<<<(unsigned)((n8 + 255) / 256), 256, 0, stream>>>(feat, featb, n8);
    // zero pad rows [N_SRC0V, M1PAD)
    int padi = (M1PAD - N_SRC0V) * K1V / 2;
    k_zero<<<(padi + 255) / 256, 256, 0, stream>>>(
        (int*)(featb + (size_t)N_SRC0V * K1V), padi);
  }
  k_transpose_bf16<<<dim3(64, 64), 256, 0, stream>>>(W1, w1t, K1V, HD1V);
  k_transpose_bf16<<<dim3(4, 8), 256, 0, stream>>>(W2, w2t, 256, 128);

  // ---- layer 1 ----
  k_gemm256_bt<<<dim3(HD1V / GBN, M1PAD / GBM), 512, 131072, stream>>>(
      featb, w1t, h1, HD1V, K1V);
  k_el_er1<<<N_SRC0V, 256, 0, stream>>>(h1, al1, ar1, el1, er1, N_DST0V);
  k_hist<<<(E0V + 255) / 256, 256, 0, stream>>>(dst0, E0V, counts1);
  k_scan<<<1, 1024, 0, stream>>>(counts1, N_DST0V, offs1, cursor1);
  k_scatter<<<(E0V + 255) / 256, 256, 0, stream>>>(dst0, E0V, cursor1, eperm1);
  k_stats<<<(N_DST0V * 8 + 255) / 256, 256, 0, stream>>>(offs1, eperm1, src0, el1, er1,
                                                         N_DST0V, 8, emax1, eden1);
  k_aggr1<<<N_DST0V, 256, 0, stream>>>(offs1, eperm1, src0, el1, er1, emax1, eden1,
                                       h1, b1, outm);

  // ---- layer 2 ----
  k_gemm_bt<float><<<dim3(1, M2PAD / BM), 256, 0, stream>>>(outm, w2t, h2, 128, 256);
  k_el_er2<<<M2PAD / 16, 256, 0, stream>>>(h2, al2, ar2, el2, er2, N_DST0V, N_DST1V);
  k_hist<<<(E1V + 255) / 256, 256, 0, stream>>>(dst1, E1V, counts2);
  k_scan<<<1, 1024, 0, stream>>>(counts2, N_DST1V, offs2, cursor2);
  k_scatter<<<(E1V + 255) / 256, 256, 0, stream>>>(dst1, E1V, cursor2, eperm2);
  k_stats<<<(N_DST1V + 255) / 256, 256, 0, stream>>>(offs2, eperm2, src1, el2, er2,
                                                     N_DST1V, 1, emax2, eden2);
  k_aggr2<<<N_DST1V, 128, 0, stream>>>(offs2, eperm2, src1, el2, er2, emax2, eden2,
                                       h2, b2, out);
}